// Round 3
// baseline (358.977 us; speedup 1.0000x reference)
//
#include <hip/hip_runtime.h>
#include <math.h>

#define NN 50
#define EMAX 256
#define XS 12   // xw/ci LDS row stride (floats): rows 16B-aligned, b128-friendly
#define SS 13   // self LDS row stride: gcd(13,32)=1 -> atomics spread all banks

// monotone f32 <-> u32 order-preserving encode (for atomicMax on floats)
__device__ __forceinline__ unsigned enc_ord(float x) {
    unsigned u = __float_as_uint(x);
    return (u & 0x80000000u) ? ~u : (u | 0x80000000u);
}
__device__ __forceinline__ float dec_ord(unsigned e) {
    return __uint_as_float((e & 0x80000000u) ? (e & 0x7FFFFFFFu) : ~e);
}

// ---------------------------------------------------------------------------
// Kernel 1: emb_proj[r][0..9]=emb[r]@conv_w, [10..19]=emb[r]@cross_w.
// Block 0 additionally writes attn_t[k][i] = attn[i][k] (for coalesced reads).
// ---------------------------------------------------------------------------
__global__ __launch_bounds__(256) void precompute_proj(
    const float* __restrict__ emb,
    const float* __restrict__ conv_w,
    const float* __restrict__ cross_w,
    const float* __restrict__ attn,
    float* __restrict__ emb_proj,
    float* __restrict__ attn_t,
    int nrows)
{
    if (blockIdx.x == 0) {
        for (int i = threadIdx.x; i < NN * NN; i += 256) {
            int k = i / NN, r = i % NN;
            attn_t[k * NN + r] = attn[r * NN + k];
        }
    }

    __shared__ float s_w[128 * 20];
    const int tid = threadIdx.x;
    for (int i = tid; i < 1280; i += 256) {
        int k = i / 10, j = i % 10;
        s_w[k * 20 + j]      = conv_w[i];
        s_w[k * 20 + 10 + j] = cross_w[i];
    }
    __syncthreads();

    const int r = blockIdx.x * 256 + tid;
    if (r >= nrows) return;

    float row[128];
    const float4* rp = (const float4*)(emb + (size_t)r * 128);
#pragma unroll
    for (int q = 0; q < 32; ++q) {
        float4 v = rp[q];
        row[q * 4 + 0] = v.x; row[q * 4 + 1] = v.y;
        row[q * 4 + 2] = v.z; row[q * 4 + 3] = v.w;
    }
    float acc[20];
#pragma unroll
    for (int j = 0; j < 20; ++j) acc[j] = 0.0f;
#pragma unroll
    for (int k = 0; k < 128; ++k) {
        float x = row[k];
#pragma unroll
        for (int j = 0; j < 20; ++j) acc[j] += x * s_w[k * 20 + j];
    }
    float4* op = (float4*)(emb_proj + (size_t)r * 20);
#pragma unroll
    for (int q = 0; q < 5; ++q)
        op[q] = make_float4(acc[q * 4], acc[q * 4 + 1], acc[q * 4 + 2], acc[q * 4 + 3]);
}

// ---------------------------------------------------------------------------
// Kernel 2: fused per-sample forward. One block (256 thr = 4 waves) / sample.
// LDS ~20 KB -> 8 blocks/CU. Matmuls/MLP in registers; weights via scalar path.
// ---------------------------------------------------------------------------
__global__ __launch_bounds__(256) void gmn_fused(
    const int* __restrict__ tok_u_all, const int* __restrict__ tok_r_all,
    const int* __restrict__ adj_u_all, const int* __restrict__ adj_r_all,
    const float* __restrict__ emb_proj,
    const float* __restrict__ attn_t,
    const float* __restrict__ conv_b,
    const float* __restrict__ assign_w,
    const float* __restrict__ mp_w1, const float* __restrict__ mp_b1,
    const float* __restrict__ mp_w2, const float* __restrict__ mp_b2,
    const float* __restrict__ ffn_w1, const float* __restrict__ ffn_b1,
    const float* __restrict__ ffn_w2, const float* __restrict__ ffn_b2,
    float* __restrict__ out, int E)
{
    const int b    = blockIdx.x;
    const int tid  = threadIdx.x;
    const int lane = tid & 63;
    const int wid  = tid >> 6;
    const int EV   = E + NN;   // real edges + self loops

    __shared__ __attribute__((aligned(16))) int   s_adj[2][2 * EMAX];
    __shared__ __attribute__((aligned(16))) float s_xw[2][NN * XS];
    __shared__ __attribute__((aligned(16))) float s_ci[2][NN * XS];
    __shared__ float s_self[2][NN * SS];
    __shared__ int   s_tok[2][NN];
    __shared__ float s_deg[2][NN];
    __shared__ unsigned s_gmax[2][20];
    __shared__ float s_t1[40];

    // ---- phase 0: stage adj (int4), tokens; init deg, gmax, self=bias
    {
        const int* au = adj_u_all + (size_t)b * 2 * E;
        const int* ar = adj_r_all + (size_t)b * 2 * E;
        const int n4 = (2 * E) / 4;
        for (int i = tid; i < 2 * n4; i += 256) {
            int g = i >= n4, k = i - g * n4;
            ((int4*)s_adj[g])[k] = ((const int4*)(g ? ar : au))[k];
        }
        for (int i = 4 * n4 + tid; i < 2 * E; i += 256) {  // tail if E%4 != 0
            s_adj[0][i] = au[i]; s_adj[1][i] = ar[i];
        }
        if (tid < 100) {
            int g = tid >= 50, r = tid - g * 50;
            s_tok[g][r] = (g ? tok_r_all : tok_u_all)[(size_t)b * 50 + r];
            s_deg[g][r] = 1.0f;   // self-loop
        }
        if (tid < 40) s_gmax[tid >= 20][tid % 20] = 0u;
        for (int i = tid; i < 1000; i += 256) {
            int g = i >= 500, rem = i - g * 500, r = rem / 10, j = rem % 10;
            s_self[g][r * SS + j] = conv_b[j];
        }
    }
    __syncthreads();

    // ---- phase 1: gather projected rows (float4 from L2) + degree atomics
    if (tid < 100) {
        int g = tid >= 50, r = tid - g * 50;
        const float* p = emb_proj + (size_t)s_tok[g][r] * 20;
        float4 v0 = ((const float4*)p)[0];
        float4 v1 = ((const float4*)p)[1];
        float4 v2 = ((const float4*)p)[2];
        float4 v3 = ((const float4*)p)[3];
        float4 v4 = ((const float4*)p)[4];
        float* xw = &s_xw[g][r * XS];
        float* ci = &s_ci[g][r * XS];
        xw[0] = v0.x; xw[1] = v0.y; xw[2] = v0.z; xw[3] = v0.w;
        xw[4] = v1.x; xw[5] = v1.y; xw[6] = v1.z; xw[7] = v1.w;
        xw[8] = v2.x; xw[9] = v2.y;
        ci[0] = v2.z; ci[1] = v2.w;
        ci[2] = v3.x; ci[3] = v3.y; ci[4] = v3.z; ci[5] = v3.w;
        ci[6] = v4.x; ci[7] = v4.y; ci[8] = v4.z; ci[9] = v4.w;
    }
    for (int e = tid; e < 2 * E; e += 256) {
        int g = e >= E, ei = e - g * E;
        atomicAdd(&s_deg[g][s_adj[g][E + ei]], 1.0f);
    }
    __syncthreads();

    // ---- phase 2: GCN aggregation (edges + self loops), rsqrt inline
    for (int e = tid; e < 2 * EV; e += 256) {
        int g = e >= EV, ei = e - g * EV;
        int src, dst;
        if (ei < E) { src = s_adj[g][ei]; dst = s_adj[g][E + ei]; }
        else        { src = dst = ei - E; }
        float nrm = rsqrtf(s_deg[g][src]) * rsqrtf(s_deg[g][dst]);
        const float* xr = &s_xw[g][src * XS];
        float4 a  = *(const float4*)xr;
        float4 c  = *(const float4*)(xr + 4);
        float2 d2 = *(const float2*)(xr + 8);
        float* sr = &s_self[g][dst * SS];
        atomicAdd(sr + 0, nrm * a.x);  atomicAdd(sr + 1, nrm * a.y);
        atomicAdd(sr + 2, nrm * a.z);  atomicAdd(sr + 3, nrm * a.w);
        atomicAdd(sr + 4, nrm * c.x);  atomicAdd(sr + 5, nrm * c.y);
        atomicAdd(sr + 6, nrm * c.z);  atomicAdd(sr + 7, nrm * c.w);
        atomicAdd(sr + 8, nrm * d2.x); atomicAdd(sr + 9, nrm * d2.y);
    }
    __syncthreads();

    // ---- phase 3: tail on waves 2,3 (one wave per graph), lane = node row
    if (wid >= 2 && lane < NN) {
        const int g = wid - 2;
        const int i = lane;

        // cross[i][:] = sum_k attn[i][k] * ci_other[k][:]   (accums in regs)
        float acc[10];
#pragma unroll
        for (int j = 0; j < 10; ++j) acc[j] = 0.0f;
        const float* cio = s_ci[g ^ 1];
        for (int k = 0; k < NN; ++k) {
            float aik = attn_t[k * NN + i];          // coalesced, L1-hot
            const float* cr = &cio[k * XS];
            float4 c0 = *(const float4*)cr;          // broadcast LDS reads
            float4 c1 = *(const float4*)(cr + 4);
            float2 c2 = *(const float2*)(cr + 8);
            acc[0] += aik * c0.x; acc[1] += aik * c0.y;
            acc[2] += aik * c0.z; acc[3] += aik * c0.w;
            acc[4] += aik * c1.x; acc[5] += aik * c1.y;
            acc[6] += aik * c1.z; acc[7] += aik * c1.w;
            acc[8] += aik * c2.x; acc[9] += aik * c2.y;
        }

        float sf[10];
#pragma unroll
        for (int j = 0; j < 10; ++j) sf[j] = s_self[g][i * SS + j];

        // cosine distance
        float dot = 0.0f, na2 = 0.0f, nc2 = 0.0f;
#pragma unroll
        for (int j = 0; j < 10; ++j) {
            float aw = assign_w[i * 10 + j];
            float a = aw * sf[j], c = aw * acc[j];
            dot += a * c; na2 += a * a; nc2 += c * c;
        }
        float dist = dot / (fmaxf(sqrtf(na2), 1e-8f) * fmaxf(sqrtf(nc2), 1e-8f));

        // h1 = relu([dist, self] @ w1 + b1)  (weights via uniform/scalar loads)
        float h1[20];
#pragma unroll
        for (int o = 0; o < 20; ++o) {
            float t = mp_b1[o] + dist * mp_w1[o];
#pragma unroll
            for (int j = 0; j < 10; ++j) t += sf[j] * mp_w1[(1 + j) * 20 + o];
            h1[o] = fmaxf(t, 0.0f);
        }
        // h2 = h1 @ w2 + b2, fold straight into ordered atomicMax (row-max pool)
#pragma unroll
        for (int o = 0; o < 20; ++o) {
            float t = mp_b2[o];
#pragma unroll
            for (int q = 0; q < 20; ++q) t += h1[q] * mp_w2[q * 20 + o];
            atomicMax(&s_gmax[g][o], enc_ord(t));
        }
    }
    __syncthreads();

    // ---- phase 4: FFN layer 1 (80->40), feat built on the fly
    if (tid < 40) {
        float acc = ffn_b1[tid];
#pragma unroll
        for (int i = 0; i < 20; ++i) {
            float gu = dec_ord(s_gmax[0][i]);
            float gr = dec_ord(s_gmax[1][i]);
            acc += gu * ffn_w1[i * 40 + tid]
                 + gr * ffn_w1[(20 + i) * 40 + tid]
                 + gu * gr * ffn_w1[(40 + i) * 40 + tid]
                 + fabsf(gu - gr) * ffn_w1[(60 + i) * 40 + tid];
        }
        s_t1[tid] = fmaxf(acc, 0.0f);
    }
    __syncthreads();

    // ---- phase 5: FFN layer 2 + sigmoid
    if (tid == 0) {
        float acc = ffn_b2[0];
#pragma unroll
        for (int o = 0; o < 40; ++o) acc += s_t1[o] * ffn_w2[o];
        out[b] = 1.0f / (1.0f + expf(-acc));
    }
}

extern "C" void kernel_launch(void* const* d_in, const int* in_sizes, int n_in,
                              void* d_out, int out_size, void* d_ws, size_t ws_size,
                              hipStream_t stream)
{
    const int*   tok_u    = (const int*)d_in[0];
    const int*   tok_r    = (const int*)d_in[1];
    const int*   adj_u    = (const int*)d_in[2];
    const int*   adj_r    = (const int*)d_in[3];
    const float* emb      = (const float*)d_in[4];
    const float* conv_w   = (const float*)d_in[5];
    const float* conv_b   = (const float*)d_in[6];
    const float* cross_w  = (const float*)d_in[7];
    const float* attn     = (const float*)d_in[8];
    const float* assign_w = (const float*)d_in[9];
    const float* mp_w1    = (const float*)d_in[10];
    const float* mp_b1    = (const float*)d_in[11];
    const float* mp_w2    = (const float*)d_in[12];
    const float* mp_b2    = (const float*)d_in[13];
    const float* ffn_w1   = (const float*)d_in[14];
    const float* ffn_b1   = (const float*)d_in[15];
    const float* ffn_w2   = (const float*)d_in[16];
    const float* ffn_b2   = (const float*)d_in[17];

    const int B     = in_sizes[0] / 50;
    const int E     = in_sizes[2] / (2 * B);
    const int nrows = in_sizes[4] / 128;

    float* emb_proj = (float*)d_ws;                      // [nrows][20]
    float* attn_t   = emb_proj + (size_t)nrows * 20;     // [50][50] transposed

    precompute_proj<<<(nrows + 255) / 256, 256, 0, stream>>>(
        emb, conv_w, cross_w, attn, emb_proj, attn_t, nrows);

    gmn_fused<<<B, 256, 0, stream>>>(
        tok_u, tok_r, adj_u, adj_r, emb_proj, attn_t, conv_b,
        assign_w, mp_w1, mp_b1, mp_w2, mp_b2,
        ffn_w1, ffn_b1, ffn_w2, ffn_b2,
        (float*)d_out, E);
}

// Round 4
// 248.137 us; speedup vs baseline: 1.4467x; 1.4467x over previous
//
#include <hip/hip_runtime.h>
#include <math.h>

#define NN 50
#define EMAX 256
#define XS 12   // xw/ci/cross LDS row stride (floats), 16B-aligned rows
#define AW 25   // A row stride in u32 words (u16-packed counts, 50 per row)
#define ASW 11  // assign_w row stride (gcd(11,32)=1)

// ---------------------------------------------------------------------------
// Kernel 1: emb_proj[r][0..9]=emb[r]@conv_w, [10..19]=emb[r]@cross_w.
// Block 0 additionally writes attn_t[k][i] = attn[i][k] (coalesced cross reads).
// ---------------------------------------------------------------------------
__global__ __launch_bounds__(256) void precompute_proj(
    const float* __restrict__ emb,
    const float* __restrict__ conv_w,
    const float* __restrict__ cross_w,
    const float* __restrict__ attn,
    float* __restrict__ emb_proj,
    float* __restrict__ attn_t,
    int nrows)
{
    if (blockIdx.x == 0) {
        for (int i = threadIdx.x; i < NN * NN; i += 256) {
            int k = i / NN, r = i % NN;
            attn_t[k * NN + r] = attn[r * NN + k];
        }
    }

    __shared__ float s_w[128 * 20];
    const int tid = threadIdx.x;
    for (int i = tid; i < 1280; i += 256) {
        int k = i / 10, j = i % 10;
        s_w[k * 20 + j]      = conv_w[i];
        s_w[k * 20 + 10 + j] = cross_w[i];
    }
    __syncthreads();

    const int r = blockIdx.x * 256 + tid;
    if (r >= nrows) return;

    float row[128];
    const float4* rp = (const float4*)(emb + (size_t)r * 128);
#pragma unroll
    for (int q = 0; q < 32; ++q) {
        float4 v = rp[q];
        row[q * 4 + 0] = v.x; row[q * 4 + 1] = v.y;
        row[q * 4 + 2] = v.z; row[q * 4 + 3] = v.w;
    }
    float acc[20];
#pragma unroll
    for (int j = 0; j < 20; ++j) acc[j] = 0.0f;
#pragma unroll
    for (int k = 0; k < 128; ++k) {
        float x = row[k];
#pragma unroll
        for (int j = 0; j < 20; ++j) acc[j] += x * s_w[k * 20 + j];
    }
    float4* op = (float4*)(emb_proj + (size_t)r * 20);
#pragma unroll
    for (int q = 0; q < 5; ++q)
        op[q] = make_float4(acc[q * 4], acc[q * 4 + 1], acc[q * 4 + 2], acc[q * 4 + 3]);
}

// ---------------------------------------------------------------------------
// Kernel 2: fused per-sample forward. One block (4 waves) per sample.
// Dense-A GCN (no per-edge scatter), wave-specialized, MLP in registers.
// ---------------------------------------------------------------------------
__global__ __launch_bounds__(256) void gmn_fused(
    const int* __restrict__ tok_u_all, const int* __restrict__ tok_r_all,
    const int* __restrict__ adj_u_all, const int* __restrict__ adj_r_all,
    const float* __restrict__ emb_proj,
    const float* __restrict__ attn_t,
    const float* __restrict__ conv_b,
    const float* __restrict__ assign_w,
    const float* __restrict__ mp_w1, const float* __restrict__ mp_b1,
    const float* __restrict__ mp_w2, const float* __restrict__ mp_b2,
    const float* __restrict__ ffn_w1, const float* __restrict__ ffn_b1,
    const float* __restrict__ ffn_w2, const float* __restrict__ ffn_b2,
    float* __restrict__ out, int E)
{
    const int b    = blockIdx.x;
    const int tid  = threadIdx.x;
    const int lane = tid & 63;
    const int wid  = tid >> 6;

    __shared__ __attribute__((aligned(16))) int      s_adj[2][2 * EMAX];  // 4 KB
    __shared__ __attribute__((aligned(16))) unsigned s_A[2][NN * AW];     // 10 KB u16-packed
    __shared__ __attribute__((aligned(16))) float    s_xw[2][NN * XS];    // dinv-scaled xw
    __shared__ __attribute__((aligned(16))) float    s_ci[2][NN * XS];
    __shared__ __attribute__((aligned(16))) float    s_cross[2][NN * XS];
    __shared__ float s_deg[2][NN];
    __shared__ float s_asw[NN * ASW];
    __shared__ float s_g[2][20];
    __shared__ float s_t1[40];

    // ---------------- P0: stage adj, zero A, stage assign_w, init deg ------
    {
        const int* au = adj_u_all + (size_t)b * 2 * E;
        const int* ar = adj_r_all + (size_t)b * 2 * E;
        const int n4 = (2 * E) >> 2;
        for (int i = tid; i < 2 * n4; i += 256) {
            int g = i >= n4, k = i - g * n4;
            ((int4*)s_adj[g])[k] = ((const int4*)(g ? ar : au))[k];
        }
        for (int i = 4 * n4 + tid; i < 2 * E; i += 256) {
            s_adj[0][i] = au[i]; s_adj[1][i] = ar[i];
        }
        uint4 z4 = make_uint4(0u, 0u, 0u, 0u);
        for (int i = tid; i < (2 * NN * AW) / 4; i += 256)
            ((uint4*)s_A)[i] = z4;
        for (int i = tid; i < NN * 10; i += 256)
            s_asw[(i / 10) * ASW + (i % 10)] = assign_w[i];
        if (tid < 2 * NN) s_deg[tid / NN][tid % NN] = 1.0f;  // self-loop
    }
    __syncthreads();

    // thread-persistent registers for waves 0,1 (g = wid, row = lane)
    float rx[10];   // own xw row (later dinv-scaled)
    float di = 0.0f;
    const bool rowner = (wid < 2) && (lane < NN);
    const int  g01    = wid & 1;

    // ---------------- P1: waves 0-1 gather; waves 2-3 build A + deg --------
    if (wid < 2) {
        if (rowner) {
            int t = (g01 ? tok_r_all : tok_u_all)[(size_t)b * NN + lane];
            const float4* p = (const float4*)(emb_proj + (size_t)t * 20);
            float4 v0 = p[0], v1 = p[1], v2 = p[2], v3 = p[3], v4 = p[4];
            rx[0] = v0.x; rx[1] = v0.y; rx[2] = v0.z; rx[3] = v0.w;
            rx[4] = v1.x; rx[5] = v1.y; rx[6] = v1.z; rx[7] = v1.w;
            rx[8] = v2.x; rx[9] = v2.y;
            float* ci = &s_ci[g01][lane * XS];
            ci[0] = v2.z; ci[1] = v2.w;
            ci[2] = v3.x; ci[3] = v3.y; ci[4] = v3.z; ci[5] = v3.w;
            ci[6] = v4.x; ci[7] = v4.y; ci[8] = v4.z; ci[9] = v4.w;
        }
    } else {
        for (int e = tid - 128; e < 2 * E; e += 128) {
            int g = e >= E, ei = e - g * E;
            int src = s_adj[g][ei];
            int dst = s_adj[g][E + ei];
            atomicAdd(&s_deg[g][dst], 1.0f);
            atomicAdd(&s_A[g][dst * AW + (src >> 1)], (src & 1) ? 0x10000u : 1u);
        }
    }
    __syncthreads();

    // ---------------- P2: waves 0-1 scale xw; waves 2-3 cross matmul -------
    if (wid < 2) {
        if (rowner) {
            di = rsqrtf(s_deg[g01][lane]);
#pragma unroll
            for (int j = 0; j < 10; ++j) rx[j] *= di;   // xw' = dinv * xw
            float* x = &s_xw[g01][lane * XS];
            *(float4*)(x)     = make_float4(rx[0], rx[1], rx[2], rx[3]);
            *(float4*)(x + 4) = make_float4(rx[4], rx[5], rx[6], rx[7]);
            *(float2*)(x + 8) = make_float2(rx[8], rx[9]);
        }
    } else if (lane < NN) {
        const int g = wid - 2;           // cross for graph g uses OTHER graph's ci
        const int i = lane;
        float acc[10];
#pragma unroll
        for (int j = 0; j < 10; ++j) acc[j] = 0.0f;
        const float* cio = s_ci[g ^ 1];
#pragma unroll 10
        for (int k = 0; k < NN; ++k) {
            float aik = attn_t[k * NN + i];          // coalesced, L1-hot
            const float* cr = &cio[k * XS];
            float4 c0 = *(const float4*)cr;          // broadcast LDS reads
            float4 c1 = *(const float4*)(cr + 4);
            float2 c2 = *(const float2*)(cr + 8);
            acc[0] += aik * c0.x; acc[1] += aik * c0.y;
            acc[2] += aik * c0.z; acc[3] += aik * c0.w;
            acc[4] += aik * c1.x; acc[5] += aik * c1.y;
            acc[6] += aik * c1.z; acc[7] += aik * c1.w;
            acc[8] += aik * c2.x; acc[9] += aik * c2.y;
        }
        float* cw = &s_cross[g][i * XS];
        *(float4*)(cw)     = make_float4(acc[0], acc[1], acc[2], acc[3]);
        *(float4*)(cw + 4) = make_float4(acc[4], acc[5], acc[6], acc[7]);
        *(float2*)(cw + 8) = make_float2(acc[8], acc[9]);
    }
    __syncthreads();

    // ---------------- P3: waves 0-1: dense self matmul + MLP + reduce ------
    if (wid < 2) {
        float h2[20];
        if (rowner) {
            const int i = lane;
            float acc[10];
#pragma unroll
            for (int j = 0; j < 10; ++j) acc[j] = rx[j];   // + I term (xw'[i])
            const unsigned* Arow = &s_A[g01][i * AW];
#pragma unroll 5
            for (int kw = 0; kw < AW; ++kw) {
                unsigned a32 = Arow[kw];                   // counts k=2kw, 2kw+1
                float c0 = (float)(a32 & 0xFFFFu);
                float c1 = (float)(a32 >> 16);
                const float* x0 = &s_xw[g01][(2 * kw) * XS];
                float4 p0 = *(const float4*)x0;
                float4 p1 = *(const float4*)(x0 + 4);
                float2 p2 = *(const float2*)(x0 + 8);
                acc[0] += c0 * p0.x; acc[1] += c0 * p0.y;
                acc[2] += c0 * p0.z; acc[3] += c0 * p0.w;
                acc[4] += c0 * p1.x; acc[5] += c0 * p1.y;
                acc[6] += c0 * p1.z; acc[7] += c0 * p1.w;
                acc[8] += c0 * p2.x; acc[9] += c0 * p2.y;
                const float* x1 = x0 + XS;
                float4 q0 = *(const float4*)x1;
                float4 q1 = *(const float4*)(x1 + 4);
                float2 q2 = *(const float2*)(x1 + 8);
                acc[0] += c1 * q0.x; acc[1] += c1 * q0.y;
                acc[2] += c1 * q0.z; acc[3] += c1 * q0.w;
                acc[4] += c1 * q1.x; acc[5] += c1 * q1.y;
                acc[6] += c1 * q1.z; acc[7] += c1 * q1.w;
                acc[8] += c1 * q2.x; acc[9] += c1 * q2.y;
            }
            float sf[10];
#pragma unroll
            for (int j = 0; j < 10; ++j) sf[j] = di * acc[j] + conv_b[j];

            // cross row + cosine
            const float* cp = &s_cross[g01][i * XS];
            float4 c0 = *(const float4*)cp;
            float4 c1 = *(const float4*)(cp + 4);
            float2 c2 = *(const float2*)(cp + 8);
            float cr[10] = { c0.x, c0.y, c0.z, c0.w, c1.x, c1.y, c1.z, c1.w, c2.x, c2.y };
            float dot = 0.0f, na2 = 0.0f, nc2 = 0.0f;
#pragma unroll
            for (int j = 0; j < 10; ++j) {
                float aw = s_asw[i * ASW + j];
                float a = aw * sf[j], c = aw * cr[j];
                dot += a * c; na2 += a * a; nc2 += c * c;
            }
            float dist = dot / (fmaxf(sqrtf(na2), 1e-8f) * fmaxf(sqrtf(nc2), 1e-8f));

            // h1 = relu([dist, self] @ w1 + b1)  (wave-uniform weight indices)
            float h1[20];
#pragma unroll
            for (int o = 0; o < 20; ++o) {
                float t = mp_b1[o] + dist * mp_w1[o];
#pragma unroll
                for (int j = 0; j < 10; ++j) t += sf[j] * mp_w1[(1 + j) * 20 + o];
                h1[o] = fmaxf(t, 0.0f);
            }
            // h2 = h1 @ w2 + b2
#pragma unroll
            for (int o = 0; o < 20; ++o) {
                float t = mp_b2[o];
#pragma unroll
                for (int q = 0; q < 20; ++q) t += h1[q] * mp_w2[q * 20 + o];
                h2[o] = t;
            }
        } else {
#pragma unroll
            for (int o = 0; o < 20; ++o) h2[o] = -INFINITY;
        }
        // wave-wide butterfly max over rows (lanes 50-63 = -inf)
#pragma unroll
        for (int o = 0; o < 20; ++o) {
            float v = h2[o];
            v = fmaxf(v, __shfl_xor(v, 1));
            v = fmaxf(v, __shfl_xor(v, 2));
            v = fmaxf(v, __shfl_xor(v, 4));
            v = fmaxf(v, __shfl_xor(v, 8));
            v = fmaxf(v, __shfl_xor(v, 16));
            v = fmaxf(v, __shfl_xor(v, 32));
            h2[o] = v;
        }
        if (lane == 0) {
#pragma unroll
            for (int o = 0; o < 20; ++o) s_g[g01][o] = h2[o];
        }
    }
    __syncthreads();

    // ---------------- P4: FFN layer 1 (80->40), feat on the fly ------------
    if (tid < 40) {
        float acc = ffn_b1[tid];
#pragma unroll
        for (int i = 0; i < 20; ++i) {
            float gu = s_g[0][i], gr = s_g[1][i];
            acc += gu * ffn_w1[i * 40 + tid]
                 + gr * ffn_w1[(20 + i) * 40 + tid]
                 + gu * gr * ffn_w1[(40 + i) * 40 + tid]
                 + fabsf(gu - gr) * ffn_w1[(60 + i) * 40 + tid];
        }
        s_t1[tid] = fmaxf(acc, 0.0f);
    }
    __syncthreads();

    // ---------------- P5: FFN layer 2 + sigmoid ----------------------------
    if (tid == 0) {
        float acc = ffn_b2[0];
#pragma unroll
        for (int o = 0; o < 40; ++o) acc += s_t1[o] * ffn_w2[o];
        out[b] = 1.0f / (1.0f + expf(-acc));
    }
}

extern "C" void kernel_launch(void* const* d_in, const int* in_sizes, int n_in,
                              void* d_out, int out_size, void* d_ws, size_t ws_size,
                              hipStream_t stream)
{
    const int*   tok_u    = (const int*)d_in[0];
    const int*   tok_r    = (const int*)d_in[1];
    const int*   adj_u    = (const int*)d_in[2];
    const int*   adj_r    = (const int*)d_in[3];
    const float* emb      = (const float*)d_in[4];
    const float* conv_w   = (const float*)d_in[5];
    const float* conv_b   = (const float*)d_in[6];
    const float* cross_w  = (const float*)d_in[7];
    const float* attn     = (const float*)d_in[8];
    const float* assign_w = (const float*)d_in[9];
    const float* mp_w1    = (const float*)d_in[10];
    const float* mp_b1    = (const float*)d_in[11];
    const float* mp_w2    = (const float*)d_in[12];
    const float* mp_b2    = (const float*)d_in[13];
    const float* ffn_w1   = (const float*)d_in[14];
    const float* ffn_b1   = (const float*)d_in[15];
    const float* ffn_w2   = (const float*)d_in[16];
    const float* ffn_b2   = (const float*)d_in[17];

    const int B     = in_sizes[0] / 50;
    const int E     = in_sizes[2] / (2 * B);
    const int nrows = in_sizes[4] / 128;

    float* emb_proj = (float*)d_ws;                      // [nrows][20]
    float* attn_t   = emb_proj + (size_t)nrows * 20;     // [50][50] transposed

    precompute_proj<<<(nrows + 255) / 256, 256, 0, stream>>>(
        emb, conv_w, cross_w, attn, emb_proj, attn_t, nrows);

    gmn_fused<<<B, 256, 0, stream>>>(
        tok_u, tok_r, adj_u, adj_r, emb_proj, attn_t, conv_b,
        assign_w, mp_w1, mp_b1, mp_w2, mp_b2,
        ffn_w1, ffn_b1, ffn_w2, ffn_b2,
        (float*)d_out, E);
}

// Round 5
// 237.775 us; speedup vs baseline: 1.5097x; 1.0436x over previous
//
#include <hip/hip_runtime.h>
#include <math.h>

#define NN 50
#define XS 12   // xw/ci LDS row stride (floats), rows 16B-aligned
#define AW 25   // A row stride in u32 words (u16-packed counts)

// ---------------------------------------------------------------------------
// Kernel 1: emb_proj[r][0..9]=emb[r]@conv_w, [10..19]=emb[r]@cross_w.
// Weights read with wave-UNIFORM indices from global -> s_load + SGPR-operand
// FMAs (zero LDS traffic). Block 0 also transposes attn into attn_t.
// ---------------------------------------------------------------------------
__global__ __launch_bounds__(256) void precompute_proj(
    const float* __restrict__ emb,
    const float* __restrict__ conv_w,
    const float* __restrict__ cross_w,
    const float* __restrict__ attn,
    float* __restrict__ emb_proj,
    float* __restrict__ attn_t,
    int nrows)
{
    if (blockIdx.x == 0) {
        for (int i = threadIdx.x; i < NN * NN; i += 256) {
            int k = i / NN, r = i % NN;
            attn_t[k * NN + r] = attn[r * NN + k];
        }
    }

    const int r = blockIdx.x * 256 + threadIdx.x;
    if (r >= nrows) return;

    const float4* rp = (const float4*)(emb + (size_t)r * 128);
    float acc[20];
#pragma unroll
    for (int j = 0; j < 20; ++j) acc[j] = 0.0f;

#pragma unroll
    for (int q = 0; q < 32; ++q) {
        float4 v = rp[q];
        float xs[4] = { v.x, v.y, v.z, v.w };
#pragma unroll
        for (int t = 0; t < 4; ++t) {
            const int k = q * 4 + t;
            const float x = xs[t];
#pragma unroll
            for (int j = 0; j < 10; ++j) {
                acc[j]      += x * conv_w[k * 10 + j];    // uniform -> s_load
                acc[10 + j] += x * cross_w[k * 10 + j];   // uniform -> s_load
            }
        }
    }

    float4* op = (float4*)(emb_proj + (size_t)r * 20);
#pragma unroll
    for (int q = 0; q < 5; ++q)
        op[q] = make_float4(acc[4 * q], acc[4 * q + 1], acc[4 * q + 2], acc[4 * q + 3]);
}

// ---------------------------------------------------------------------------
// Kernel 2: fused forward. Block = 128 threads (2 waves), one sample/block.
// Wave g owns graph g end-to-end; only cross-wave data: s_ci, s_g.
// ---------------------------------------------------------------------------
__global__ __launch_bounds__(128) void gmn_fused(
    const int* __restrict__ tok_u_all, const int* __restrict__ tok_r_all,
    const int* __restrict__ adj_u_all, const int* __restrict__ adj_r_all,
    const float* __restrict__ emb_proj,
    const float* __restrict__ attn_t,
    const float* __restrict__ conv_b,
    const float* __restrict__ assign_w,
    const float* __restrict__ mp_w1, const float* __restrict__ mp_b1,
    const float* __restrict__ mp_w2, const float* __restrict__ mp_b2,
    const float* __restrict__ ffn_w1, const float* __restrict__ ffn_b1,
    const float* __restrict__ ffn_w2, const float* __restrict__ ffn_b2,
    float* __restrict__ out, int E)
{
    const int b    = blockIdx.x;
    const int tid  = threadIdx.x;
    const int lane = tid & 63;
    const int g    = tid >> 6;          // wave id == graph id

    __shared__ __attribute__((aligned(16))) unsigned s_A[2][NN * AW];   // 10 KB
    __shared__ __attribute__((aligned(16))) float    s_xw[2][NN * XS];  // 4.8 KB
    __shared__ __attribute__((aligned(16))) float    s_ci[2][NN * XS];  // 4.8 KB
    __shared__ float s_deg[2][NN];
    __shared__ __attribute__((aligned(16))) float s_g[2][24];

    // ---- P1: zero A, init deg; gather own rows; build A from global adj ----
    for (int i = lane; i < NN * AW; i += 64) s_A[g][i] = 0u;
    if (lane < NN) s_deg[g][lane] = 1.0f;      // self-loop

    float rx[10];
#pragma unroll
    for (int j = 0; j < 10; ++j) rx[j] = 0.0f;

    if (lane < NN) {
        const int t = (g ? tok_r_all : tok_u_all)[(size_t)b * NN + lane];
        const float4* p = (const float4*)(emb_proj + (size_t)t * 20);
        float4 v0 = p[0], v1 = p[1], v2 = p[2], v3 = p[3], v4 = p[4];
        rx[0] = v0.x; rx[1] = v0.y; rx[2] = v0.z; rx[3] = v0.w;
        rx[4] = v1.x; rx[5] = v1.y; rx[6] = v1.z; rx[7] = v1.w;
        rx[8] = v2.x; rx[9] = v2.y;
        float* ci = &s_ci[g][lane * XS];
        *(float4*)(ci)     = make_float4(v2.z, v2.w, v3.x, v3.y);
        *(float4*)(ci + 4) = make_float4(v3.z, v3.w, v4.x, v4.y);
        *(float2*)(ci + 8) = make_float2(v4.z, v4.w);
    }
    {
        const int* adj = (g ? adj_r_all : adj_u_all) + (size_t)b * 2 * E;
        for (int e = lane; e < E; e += 64) {
            int src = adj[e], dst = adj[E + e];
            atomicAdd(&s_deg[g][dst], 1.0f);
            atomicAdd(&s_A[g][dst * AW + (src >> 1)], (src & 1) ? 0x10000u : 1u);
        }
    }
    __syncthreads();   // publishes s_ci across waves (A/deg are own-wave)

    // ---- P2: scale xw, cross (regs), self (dense A), MLP, butterfly max ----
    float di = 0.0f;
    if (lane < NN) {
        di = rsqrtf(s_deg[g][lane]);
#pragma unroll
        for (int j = 0; j < 10; ++j) rx[j] *= di;     // xw' = dinv * xw
        float* x = &s_xw[g][lane * XS];
        *(float4*)(x)     = make_float4(rx[0], rx[1], rx[2], rx[3]);
        *(float4*)(x + 4) = make_float4(rx[4], rx[5], rx[6], rx[7]);
        *(float2*)(x + 8) = make_float2(rx[8], rx[9]);
    }

    float h2[20];
#pragma unroll
    for (int o = 0; o < 20; ++o) h2[o] = -INFINITY;

    if (lane < NN) {
        const int i = lane;

        // cross[i][:] = sum_k attn[i][k] * ci_other[k][:]  (regs, no LDS out)
        float cr[10];
#pragma unroll
        for (int j = 0; j < 10; ++j) cr[j] = 0.0f;
        const float* cio = s_ci[g ^ 1];
#pragma unroll 10
        for (int k = 0; k < NN; ++k) {
            float aik = attn_t[k * NN + i];            // coalesced, L1-hot
            const float* crow = &cio[k * XS];
            float4 c0 = *(const float4*)crow;          // broadcast LDS reads
            float4 c1 = *(const float4*)(crow + 4);
            float2 c2 = *(const float2*)(crow + 8);
            cr[0] += aik * c0.x; cr[1] += aik * c0.y;
            cr[2] += aik * c0.z; cr[3] += aik * c0.w;
            cr[4] += aik * c1.x; cr[5] += aik * c1.y;
            cr[6] += aik * c1.z; cr[7] += aik * c1.w;
            cr[8] += aik * c2.x; cr[9] += aik * c2.y;
        }

        // self[i][:] = di * (xw'[i] + sum_k A[i][k] * xw'[k]) + b
        float acc[10];
#pragma unroll
        for (int j = 0; j < 10; ++j) acc[j] = rx[j];   // identity term
        const unsigned* Arow = &s_A[g][i * AW];        // stride 25: conflict-free
#pragma unroll
        for (int kw = 0; kw < AW; ++kw) {
            unsigned a32 = Arow[kw];
            float c0 = (float)(a32 & 0xFFFFu);
            float c1 = (float)(a32 >> 16);
            const float* x0 = &s_xw[g][(2 * kw) * XS]; // uniform addr: broadcast
            float4 p0 = *(const float4*)x0;
            float4 p1 = *(const float4*)(x0 + 4);
            float2 p2 = *(const float2*)(x0 + 8);
            acc[0] += c0 * p0.x; acc[1] += c0 * p0.y;
            acc[2] += c0 * p0.z; acc[3] += c0 * p0.w;
            acc[4] += c0 * p1.x; acc[5] += c0 * p1.y;
            acc[6] += c0 * p1.z; acc[7] += c0 * p1.w;
            acc[8] += c0 * p2.x; acc[9] += c0 * p2.y;
            const float* x1 = x0 + XS;
            float4 q0 = *(const float4*)x1;
            float4 q1 = *(const float4*)(x1 + 4);
            float2 q2 = *(const float2*)(x1 + 8);
            acc[0] += c1 * q0.x; acc[1] += c1 * q0.y;
            acc[2] += c1 * q0.z; acc[3] += c1 * q0.w;
            acc[4] += c1 * q1.x; acc[5] += c1 * q1.y;
            acc[6] += c1 * q1.z; acc[7] += c1 * q1.w;
            acc[8] += c1 * q2.x; acc[9] += c1 * q2.y;
        }
        float sf[10];
#pragma unroll
        for (int j = 0; j < 10; ++j) sf[j] = di * acc[j] + conv_b[j];

        // cosine distance
        float dot = 0.0f, na2 = 0.0f, nc2 = 0.0f;
        const float2* awp = (const float2*)(assign_w + i * 10);
#pragma unroll
        for (int q = 0; q < 5; ++q) {
            float2 wv = awp[q];
            float a0 = wv.x * sf[2 * q],     c0 = wv.x * cr[2 * q];
            float a1 = wv.y * sf[2 * q + 1], c1 = wv.y * cr[2 * q + 1];
            dot += a0 * c0 + a1 * c1;
            na2 += a0 * a0 + a1 * a1;
            nc2 += c0 * c0 + c1 * c1;
        }
        float dist = dot / (fmaxf(sqrtf(na2), 1e-8f) * fmaxf(sqrtf(nc2), 1e-8f));

        // h1 = relu([dist, self] @ w1 + b1)  (weights uniform -> SGPR operands)
        float h1[20];
#pragma unroll
        for (int o = 0; o < 20; ++o) {
            float t = mp_b1[o] + dist * mp_w1[o];
#pragma unroll
            for (int j = 0; j < 10; ++j) t += sf[j] * mp_w1[(1 + j) * 20 + o];
            h1[o] = fmaxf(t, 0.0f);
        }
        // h2 = h1 @ w2 + b2
#pragma unroll
        for (int o = 0; o < 20; ++o) {
            float t = mp_b2[o];
#pragma unroll
            for (int q = 0; q < 20; ++q) t += h1[q] * mp_w2[q * 20 + o];
            h2[o] = t;
        }
    }

    // wave-wide butterfly max over rows (lanes 50-63 hold -inf)
#pragma unroll
    for (int o = 0; o < 20; ++o) {
        float v = h2[o];
        v = fmaxf(v, __shfl_xor(v, 1));
        v = fmaxf(v, __shfl_xor(v, 2));
        v = fmaxf(v, __shfl_xor(v, 4));
        v = fmaxf(v, __shfl_xor(v, 8));
        v = fmaxf(v, __shfl_xor(v, 16));
        v = fmaxf(v, __shfl_xor(v, 32));
        h2[o] = v;
    }
    if (lane == 0) {
        *(float4*)&s_g[g][0]  = make_float4(h2[0],  h2[1],  h2[2],  h2[3]);
        *(float4*)&s_g[g][4]  = make_float4(h2[4],  h2[5],  h2[6],  h2[7]);
        *(float4*)&s_g[g][8]  = make_float4(h2[8],  h2[9],  h2[10], h2[11]);
        *(float4*)&s_g[g][12] = make_float4(h2[12], h2[13], h2[14], h2[15]);
        *(float4*)&s_g[g][16] = make_float4(h2[16], h2[17], h2[18], h2[19]);
    }
    __syncthreads();

    // ---- P3: FFN on wave 0 ------------------------------------------------
    if (g == 0) {
        float p = 0.0f;
        if (lane < 40) {
            float acc = ffn_b1[lane];
#pragma unroll
            for (int i = 0; i < 20; ++i) {
                float gu = s_g[0][i], gr = s_g[1][i];
                acc += gu * ffn_w1[i * 40 + lane]
                     + gr * ffn_w1[(20 + i) * 40 + lane]
                     + gu * gr * ffn_w1[(40 + i) * 40 + lane]
                     + fabsf(gu - gr) * ffn_w1[(60 + i) * 40 + lane];
            }
            p = fmaxf(acc, 0.0f) * ffn_w2[lane];
        }
        p += __shfl_xor(p, 1);  p += __shfl_xor(p, 2);  p += __shfl_xor(p, 4);
        p += __shfl_xor(p, 8);  p += __shfl_xor(p, 16); p += __shfl_xor(p, 32);
        if (lane == 0)
            out[b] = 1.0f / (1.0f + expf(-(p + ffn_b2[0])));
    }
}

extern "C" void kernel_launch(void* const* d_in, const int* in_sizes, int n_in,
                              void* d_out, int out_size, void* d_ws, size_t ws_size,
                              hipStream_t stream)
{
    const int*   tok_u    = (const int*)d_in[0];
    const int*   tok_r    = (const int*)d_in[1];
    const int*   adj_u    = (const int*)d_in[2];
    const int*   adj_r    = (const int*)d_in[3];
    const float* emb      = (const float*)d_in[4];
    const float* conv_w   = (const float*)d_in[5];
    const float* conv_b   = (const float*)d_in[6];
    const float* cross_w  = (const float*)d_in[7];
    const float* attn     = (const float*)d_in[8];
    const float* assign_w = (const float*)d_in[9];
    const float* mp_w1    = (const float*)d_in[10];
    const float* mp_b1    = (const float*)d_in[11];
    const float* mp_w2    = (const float*)d_in[12];
    const float* mp_b2    = (const float*)d_in[13];
    const float* ffn_w1   = (const float*)d_in[14];
    const float* ffn_b1   = (const float*)d_in[15];
    const float* ffn_w2   = (const float*)d_in[16];
    const float* ffn_b2   = (const float*)d_in[17];

    const int B     = in_sizes[0] / 50;
    const int E     = in_sizes[2] / (2 * B);
    const int nrows = in_sizes[4] / 128;

    float* emb_proj = (float*)d_ws;                      // [nrows][20]
    float* attn_t   = emb_proj + (size_t)nrows * 20;     // [50][50] transposed

    precompute_proj<<<(nrows + 255) / 256, 256, 0, stream>>>(
        emb, conv_w, cross_w, attn, emb_proj, attn_t, nrows);

    gmn_fused<<<B, 128, 0, stream>>>(
        tok_u, tok_r, adj_u, adj_r, emb_proj, attn_t, conv_b,
        assign_w, mp_w1, mp_b1, mp_w2, mp_b2,
        ffn_w1, ffn_b1, ffn_w2, ffn_b2,
        (float*)d_out, E);
}

// Round 6
// 183.927 us; speedup vs baseline: 1.9517x; 1.2928x over previous
//
#include <hip/hip_runtime.h>
#include <math.h>

#define NN 50
#define XS 12    // xw/ci LDS row stride (floats), rows 16B-aligned
#define AWW 13   // A row words (u8-packed counts, 4 per u32, 52 slots >= 50)

// ---------------------------------------------------------------------------
// Kernel 1: emb_proj[r][0..9]=emb[r]@conv_w, [10..19]=emb[r]@cross_w.
// Block = 256 thr = 4 waves; wave w handles j-group w for rows blockIdx*64+lane.
// (w, j0) are wave-uniform -> weight loads scalarize to s_load; rows L1-shared
// across the 4 waves. Block 0 also transposes attn into attn_t.
// ---------------------------------------------------------------------------
__global__ __launch_bounds__(256) void precompute_proj(
    const float* __restrict__ emb,
    const float* __restrict__ conv_w,
    const float* __restrict__ cross_w,
    const float* __restrict__ attn,
    float* __restrict__ emb_proj,
    float* __restrict__ attn_t,
    int nrows)
{
    if (blockIdx.x == 0) {
        for (int i = threadIdx.x; i < NN * NN; i += 256) {
            int k = i / NN, r = i % NN;
            attn_t[k * NN + r] = attn[r * NN + k];
        }
    }
    const int lane = threadIdx.x & 63;
    const int w    = threadIdx.x >> 6;           // wave-uniform j-group
    const int r    = blockIdx.x * 64 + lane;
    if (r >= nrows) return;

    const float* wb = (w < 2) ? conv_w : cross_w;
    const int j0 = (w & 1) * 5;

    float acc[5] = {0.0f, 0.0f, 0.0f, 0.0f, 0.0f};
    const float4* rp = (const float4*)(emb + (size_t)r * 128);
#pragma unroll
    for (int q = 0; q < 32; ++q) {
        float4 v = rp[q];
        const float xs[4] = { v.x, v.y, v.z, v.w };
#pragma unroll
        for (int t = 0; t < 4; ++t) {
            const int k = 4 * q + t;
#pragma unroll
            for (int jj = 0; jj < 5; ++jj)
                acc[jj] += xs[t] * wb[k * 10 + j0 + jj];   // uniform -> s_load
        }
    }
    float* op = emb_proj + (size_t)r * 20 + w * 5;
#pragma unroll
    for (int jj = 0; jj < 5; ++jj) op[jj] = acc[jj];
}

// ---------------------------------------------------------------------------
// Kernel 2: fused forward. Block = 128 threads (2 waves), one sample/block.
// Wave g owns graph g. A is u8-packed in LDS; own A row cached in VGPRs;
// deg derived from A row bytesum (no deg atomics, no s_deg).
// LDS ~14.9 KB -> 10 blocks/CU.
// ---------------------------------------------------------------------------
__global__ __launch_bounds__(128, 5) void gmn_fused(
    const int* __restrict__ tok_u_all, const int* __restrict__ tok_r_all,
    const int* __restrict__ adj_u_all, const int* __restrict__ adj_r_all,
    const float* __restrict__ emb_proj,
    const float* __restrict__ attn_t,
    const float* __restrict__ conv_b,
    const float* __restrict__ assign_w,
    const float* __restrict__ mp_w1, const float* __restrict__ mp_b1,
    const float* __restrict__ mp_w2, const float* __restrict__ mp_b2,
    const float* __restrict__ ffn_w1, const float* __restrict__ ffn_b1,
    const float* __restrict__ ffn_w2, const float* __restrict__ ffn_b2,
    float* __restrict__ out, int E)
{
    const int b    = blockIdx.x;
    const int tid  = threadIdx.x;
    const int lane = tid & 63;
    const int g    = tid >> 6;          // wave id == graph id

    __shared__ __attribute__((aligned(16))) unsigned s_A[2][NN * AWW];  // 5200 B
    __shared__ __attribute__((aligned(16))) float    s_xw[2][52 * XS];  // 4992 B (rows 50,51 zero)
    __shared__ __attribute__((aligned(16))) float    s_ci[2][NN * XS];  // 4800 B
    __shared__ __attribute__((aligned(16))) float    s_g2[2][24];

    // ---- P1: zero A + xw pad rows; gather own rows; build A from edges ----
    for (int i = lane; i < NN * AWW; i += 64) s_A[g][i] = 0u;
    for (int i = lane; i < 2 * XS; i += 64) s_xw[g][50 * XS + i] = 0.0f;

    float rx[10];
#pragma unroll
    for (int j = 0; j < 10; ++j) rx[j] = 0.0f;

    if (lane < NN) {
        const int t = (g ? tok_r_all : tok_u_all)[(size_t)b * NN + lane];
        const float4* p = (const float4*)(emb_proj + (size_t)t * 20);
        float4 v0 = p[0], v1 = p[1], v2 = p[2], v3 = p[3], v4 = p[4];
        rx[0] = v0.x; rx[1] = v0.y; rx[2] = v0.z; rx[3] = v0.w;
        rx[4] = v1.x; rx[5] = v1.y; rx[6] = v1.z; rx[7] = v1.w;
        rx[8] = v2.x; rx[9] = v2.y;
        float* ci = &s_ci[g][lane * XS];
        *(float4*)(ci)     = make_float4(v2.z, v2.w, v3.x, v3.y);
        *(float4*)(ci + 4) = make_float4(v3.z, v3.w, v4.x, v4.y);
        *(float2*)(ci + 8) = make_float2(v4.z, v4.w);
    }
    {
        const int* adj = (g ? adj_r_all : adj_u_all) + (size_t)b * 2 * E;
        for (int e = lane; e < E; e += 64) {
            int src = adj[e], dst = adj[E + e];
            atomicAdd(&s_A[g][dst * AWW + (src >> 2)], 1u << ((src & 3) * 8));
        }
    }

    // ---- P2: own A row -> VGPRs; deg = 1 + bytesum; scale xw; publish ----
    unsigned arow[AWW];
    float di = 0.0f;
    if (lane < NN) {
        unsigned s = 0;
#pragma unroll
        for (int kw = 0; kw < AWW; ++kw) {
            unsigned a = s_A[g][lane * AWW + kw];     // after own-wave atomics
            arow[kw] = a;
            s += (a & 0xFFu) + ((a >> 8) & 0xFFu) + ((a >> 16) & 0xFFu) + (a >> 24);
        }
        di = rsqrtf(1.0f + (float)s);
#pragma unroll
        for (int j = 0; j < 10; ++j) rx[j] *= di;     // xw' = dinv * xw
        float* x = &s_xw[g][lane * XS];
        *(float4*)(x)     = make_float4(rx[0], rx[1], rx[2], rx[3]);
        *(float4*)(x + 4) = make_float4(rx[4], rx[5], rx[6], rx[7]);
        *(float2*)(x + 8) = make_float2(rx[8], rx[9]);
    }
    __syncthreads();   // publishes s_ci (cross-wave) and s_xw

    // ---- P3: cross (regs), self (register A row), cosine, MLP ----
    float h2[20];
#pragma unroll
    for (int o = 0; o < 20; ++o) h2[o] = -INFINITY;

    if (lane < NN) {
        const int i = lane;

        // cross[i][:] = sum_k attn[i][k] * ci_other[k][:]
        float cr[10];
#pragma unroll
        for (int j = 0; j < 10; ++j) cr[j] = 0.0f;
        const float* cio = s_ci[g ^ 1];
#pragma unroll 10
        for (int k = 0; k < NN; ++k) {
            float aik = attn_t[k * NN + i];            // coalesced, L1-hot
            const float* crow = &cio[k * XS];
            float4 c0 = *(const float4*)crow;          // uniform broadcast LDS
            float4 c1 = *(const float4*)(crow + 4);
            float2 c2 = *(const float2*)(crow + 8);
            cr[0] += aik * c0.x; cr[1] += aik * c0.y;
            cr[2] += aik * c0.z; cr[3] += aik * c0.w;
            cr[4] += aik * c1.x; cr[5] += aik * c1.y;
            cr[6] += aik * c1.z; cr[7] += aik * c1.w;
            cr[8] += aik * c2.x; cr[9] += aik * c2.y;
        }

        // self[i][:] = di*(xw'[i] + sum_k A[i][k]*xw'[k]) + b   (A from VGPRs)
        float acc[10];
#pragma unroll
        for (int j = 0; j < 10; ++j) acc[j] = rx[j];   // identity term
#pragma unroll
        for (int kw = 0; kw < AWW; ++kw) {
            unsigned a = arow[kw];
            float c0 = (float)(a & 0xFFu);
            float c1 = (float)((a >> 8) & 0xFFu);
            float c2 = (float)((a >> 16) & 0xFFu);
            float c3 = (float)(a >> 24);
            const float* x0 = &s_xw[g][(4 * kw) * XS];
#pragma unroll
            for (int t = 0; t < 4; ++t) {
                const float c = (t == 0) ? c0 : (t == 1) ? c1 : (t == 2) ? c2 : c3;
                const float* xr = x0 + t * XS;         // uniform broadcast LDS
                float4 p0 = *(const float4*)xr;
                float4 p1 = *(const float4*)(xr + 4);
                float2 p2 = *(const float2*)(xr + 8);
                acc[0] += c * p0.x; acc[1] += c * p0.y;
                acc[2] += c * p0.z; acc[3] += c * p0.w;
                acc[4] += c * p1.x; acc[5] += c * p1.y;
                acc[6] += c * p1.z; acc[7] += c * p1.w;
                acc[8] += c * p2.x; acc[9] += c * p2.y;
            }
        }
        float sf[10];
#pragma unroll
        for (int j = 0; j < 10; ++j) sf[j] = di * acc[j] + conv_b[j];

        // cosine distance
        float dot = 0.0f, na2 = 0.0f, nc2 = 0.0f;
        const float2* awp = (const float2*)(assign_w + i * 10);
#pragma unroll
        for (int q = 0; q < 5; ++q) {
            float2 wv = awp[q];
            float a0 = wv.x * sf[2 * q],     d0 = wv.x * cr[2 * q];
            float a1 = wv.y * sf[2 * q + 1], d1 = wv.y * cr[2 * q + 1];
            dot += a0 * d0 + a1 * d1;
            na2 += a0 * a0 + a1 * a1;
            nc2 += d0 * d0 + d1 * d1;
        }
        float dist = dot / (fmaxf(sqrtf(na2), 1e-8f) * fmaxf(sqrtf(nc2), 1e-8f));

        // h1 = relu([dist, self] @ w1 + b1)  (weights uniform -> SGPR operands)
        float h1[20];
#pragma unroll
        for (int o = 0; o < 20; ++o) {
            float t = mp_b1[o] + dist * mp_w1[o];
#pragma unroll
            for (int j = 0; j < 10; ++j) t += sf[j] * mp_w1[(1 + j) * 20 + o];
            h1[o] = fmaxf(t, 0.0f);
        }
        // h2 = h1 @ w2 + b2
#pragma unroll
        for (int o = 0; o < 20; ++o) {
            float t = mp_b2[o];
#pragma unroll
            for (int q = 0; q < 20; ++q) t += h1[q] * mp_w2[q * 20 + o];
            h2[o] = t;
        }
    }

    // wave-wide butterfly max over rows (lanes 50-63 hold -inf)
#pragma unroll
    for (int o = 0; o < 20; ++o) {
        float v = h2[o];
        v = fmaxf(v, __shfl_xor(v, 1));
        v = fmaxf(v, __shfl_xor(v, 2));
        v = fmaxf(v, __shfl_xor(v, 4));
        v = fmaxf(v, __shfl_xor(v, 8));
        v = fmaxf(v, __shfl_xor(v, 16));
        v = fmaxf(v, __shfl_xor(v, 32));
        h2[o] = v;
    }
    if (lane == 0) {
        *(float4*)&s_g2[g][0]  = make_float4(h2[0],  h2[1],  h2[2],  h2[3]);
        *(float4*)&s_g2[g][4]  = make_float4(h2[4],  h2[5],  h2[6],  h2[7]);
        *(float4*)&s_g2[g][8]  = make_float4(h2[8],  h2[9],  h2[10], h2[11]);
        *(float4*)&s_g2[g][12] = make_float4(h2[12], h2[13], h2[14], h2[15]);
        *(float4*)&s_g2[g][16] = make_float4(h2[16], h2[17], h2[18], h2[19]);
    }
    __syncthreads();

    // ---- P4: FFN on wave 0 ------------------------------------------------
    if (g == 0) {
        float p = 0.0f;
        if (lane < 40) {
            float acc = ffn_b1[lane];
#pragma unroll
            for (int i = 0; i < 20; ++i) {
                float gu = s_g2[0][i], gr = s_g2[1][i];
                acc += gu * ffn_w1[i * 40 + lane]
                     + gr * ffn_w1[(20 + i) * 40 + lane]
                     + gu * gr * ffn_w1[(40 + i) * 40 + lane]
                     + fabsf(gu - gr) * ffn_w1[(60 + i) * 40 + lane];
            }
            p = fmaxf(acc, 0.0f) * ffn_w2[lane];
        }
        p += __shfl_xor(p, 1);  p += __shfl_xor(p, 2);  p += __shfl_xor(p, 4);
        p += __shfl_xor(p, 8);  p += __shfl_xor(p, 16); p += __shfl_xor(p, 32);
        if (lane == 0)
            out[b] = 1.0f / (1.0f + expf(-(p + ffn_b2[0])));
    }
}

extern "C" void kernel_launch(void* const* d_in, const int* in_sizes, int n_in,
                              void* d_out, int out_size, void* d_ws, size_t ws_size,
                              hipStream_t stream)
{
    const int*   tok_u    = (const int*)d_in[0];
    const int*   tok_r    = (const int*)d_in[1];
    const int*   adj_u    = (const int*)d_in[2];
    const int*   adj_r    = (const int*)d_in[3];
    const float* emb      = (const float*)d_in[4];
    const float* conv_w   = (const float*)d_in[5];
    const float* conv_b   = (const float*)d_in[6];
    const float* cross_w  = (const float*)d_in[7];
    const float* attn     = (const float*)d_in[8];
    const float* assign_w = (const float*)d_in[9];
    const float* mp_w1    = (const float*)d_in[10];
    const float* mp_b1    = (const float*)d_in[11];
    const float* mp_w2    = (const float*)d_in[12];
    const float* mp_b2    = (const float*)d_in[13];
    const float* ffn_w1   = (const float*)d_in[14];
    const float* ffn_b1   = (const float*)d_in[15];
    const float* ffn_w2   = (const float*)d_in[16];
    const float* ffn_b2   = (const float*)d_in[17];

    const int B     = in_sizes[0] / 50;
    const int E     = in_sizes[2] / (2 * B);
    const int nrows = in_sizes[4] / 128;

    float* emb_proj = (float*)d_ws;                      // [nrows][20]
    float* attn_t   = emb_proj + (size_t)nrows * 20;     // [50][50] transposed

    precompute_proj<<<(nrows + 63) / 64, 256, 0, stream>>>(
        emb, conv_w, cross_w, attn, emb_proj, attn_t, nrows);

    gmn_fused<<<B, 128, 0, stream>>>(
        tok_u, tok_r, adj_u, adj_r, emb_proj, attn_t, conv_b,
        assign_w, mp_w1, mp_b1, mp_w2, mp_b2,
        ffn_w1, ffn_b1, ffn_w2, ffn_b2,
        (float*)d_out, E);
}